// Round 9
// baseline (66.465 us; speedup 1.0000x reference)
//
#include <hip/hip_runtime.h>
#include <math.h>

// Problem: x (64, 4096) f32, A (4096, 1024) f32.
// out[b,i] = max_k( x[b,i] * sigmoid(A[i,k]) )
//          = x[b,i] * sigmoid( x[b,i] >= 0 ? max_k A[i,k] : min_k A[i,k] )
// (sigmoid monotone increasing; scaling by a >=0 / <0 scalar selects the
//  max / min argument. Exact under FP rounding — verified absmax 0.0 in R8.)
//
// Single fused dispatch, 256 blocks (1/CU) x 512 threads. Block owns 16 rows
// of A: phase 1 computes sigmoid(rowmin/rowmax) into LDS, phase 2 writes the
// 64x16 output slab. Compulsory traffic 18 MB (~3 us); measured headline is
// dominated by the harness's 256 MiB d_ws re-poison (~43 us @ 78% HBM peak).

#define BATCH          64
#define SIZE_IN        4096
#define SIZE_OUT       1024
#define ROWS_PER_BLOCK 16
#define BLOCK          512

__global__ __launch_bounds__(BLOCK) void fused_minmax_scale(
    const float* __restrict__ x,     // [BATCH][SIZE_IN]
    const float* __restrict__ A,     // [SIZE_IN][SIZE_OUT]
    float* __restrict__ out)         // [BATCH][SIZE_IN]
{
    __shared__ __align__(16) float s_hi[ROWS_PER_BLOCK];  // sigmoid(rowmax)
    __shared__ __align__(16) float s_lo[ROWS_PER_BLOCK];  // sigmoid(rowmin)

    const int wave = threadIdx.x >> 6;   // 0..7
    const int lane = threadIdx.x & 63;
    const int r0   = blockIdx.x * ROWS_PER_BLOCK;

    // ---- Prefetch phase-2 operand BEFORE the barrier (load can't be hoisted
    // across __syncthreads). Threads 0..255 own the 64x16 slab as float4:
    // b = t>>2 (0..63), li = (t&3)*4 — 4 consecutive lanes cover one
    // contiguous 64 B segment of batch row b. Waves 4..7 skip (wave-uniform).
    const int t  = threadIdx.x;
    const int b  = t >> 2;
    const int li = (t & 3) * 4;
    const size_t xoff = (size_t)b * SIZE_IN + r0 + li;
    float4 xv;
    if (t < 256) xv = *reinterpret_cast<const float4*>(x + xoff);

    // ---- Phase 1: per-row min/max of A. 8 waves x 2 rows each = 16 rows. ----
    // Issue ALL loads first (8 dwordx4 in flight per wave; the block's whole
    // 64 KB slab), then reduce — one burst fetch, one latency wait.
    float4 v[2][4];
#pragma unroll
    for (int rr = 0; rr < 2; ++rr) {
        const int row = r0 + wave + rr * 8;
        const float4* __restrict__ Arow =
            reinterpret_cast<const float4*>(A + (size_t)row * SIZE_OUT);
#pragma unroll
        for (int j = 0; j < 4; ++j)
            v[rr][j] = Arow[j * 64 + lane];   // coalesced: 1 KB/wave/instr
    }

#pragma unroll
    for (int rr = 0; rr < 2; ++rr) {
        float mx = -INFINITY;
        float mn =  INFINITY;
#pragma unroll
        for (int j = 0; j < 4; ++j) {
            const float4 w = v[rr][j];
            mx = fmaxf(mx, fmaxf(fmaxf(w.x, w.y), fmaxf(w.z, w.w)));
            mn = fminf(mn, fminf(fminf(w.x, w.y), fminf(w.z, w.w)));
        }
        // 64-lane butterfly (wave = 64 on CDNA4); sigmoid on all lanes (VALU
        // idle anyway), single-instruction-predicated LDS store from lane 0.
#pragma unroll
        for (int off = 32; off > 0; off >>= 1) {
            mx = fmaxf(mx, __shfl_xor(mx, off));
            mn = fminf(mn, __shfl_xor(mn, off));
        }
        const float hi = 1.0f / (1.0f + expf(-mx));
        const float lo = 1.0f / (1.0f + expf(-mn));
        if (lane == 0) {
            const int lrow = wave + rr * 8;
            s_hi[lrow] = hi;
            s_lo[lrow] = lo;
        }
    }
    __syncthreads();

    // ---- Phase 2: 64x16 output slab, float4 per thread (threads 0..255). ---
    // LDS reads are 4-way-aliased broadcasts; x already in registers.
    if (t < 256) {
        const float4 hi = *reinterpret_cast<const float4*>(&s_hi[li]);
        const float4 lo = *reinterpret_cast<const float4*>(&s_lo[li]);

        float4 o;
        o.x = xv.x * (xv.x >= 0.0f ? hi.x : lo.x);
        o.y = xv.y * (xv.y >= 0.0f ? hi.y : lo.y);
        o.z = xv.z * (xv.z >= 0.0f ? hi.z : lo.z);
        o.w = xv.w * (xv.w >= 0.0f ? hi.w : lo.w);
        *reinterpret_cast<float4*>(out + xoff) = o;
    }
}

extern "C" void kernel_launch(void* const* d_in, const int* in_sizes, int n_in,
                              void* d_out, int out_size, void* d_ws, size_t ws_size,
                              hipStream_t stream) {
    const float* x = (const float*)d_in[0];   // (64, 4096)
    const float* A = (const float*)d_in[1];   // (4096, 1024)
    float* out = (float*)d_out;               // (64, 4096)

    fused_minmax_scale<<<SIZE_IN / ROWS_PER_BLOCK, BLOCK, 0, stream>>>(x, A, out);
}